// Round 1
// baseline (788.093 us; speedup 1.0000x reference)
//
#include <hip/hip_runtime.h>
#include <hip/hip_bf16.h>

// Problem constants: B=2, T=4096, C=768, H=12, D=64
#define T_DIM 4096
#define H_N 12
#define D_H 64
#define C_DIM 768
#define B_N 2

typedef short bf16x8 __attribute__((ext_vector_type(8)));
typedef float f32x4 __attribute__((ext_vector_type(4)));

__device__ __forceinline__ short f2bf(float f) {
    union { float f; unsigned u; } x; x.f = f;
    unsigned r = x.u + 0x7fffu + ((x.u >> 16) & 1u);   // RNE
    return (short)(r >> 16);
}

// ---------------------------------------------------------------------------
// Kernel 1: qkv = x @ Wqkv + bqkv ; scatter to Q,K,V [B,H,T,D] bf16; Q *= 0.125
// M=8192, K=768, N=2304. grid(18,64), block 256 (4 waves, 2x2 of 64x64).
// ---------------------------------------------------------------------------
__global__ __launch_bounds__(256) void qkv_kernel(
    const float* __restrict__ x, const float* __restrict__ W,
    const float* __restrict__ bias,
    short* __restrict__ Qo, short* __restrict__ Ko, short* __restrict__ Vo)
{
    __shared__ short As[128][40];   // [m][k], stride 80B (16B-aligned, bank-spread)
    __shared__ short Bs[128][40];   // [n][k] (B transposed in LDS for contiguous frags)

    const int tid  = threadIdx.x;
    const int wave = tid >> 6, lane = tid & 63;
    const int quad = lane >> 4, l16 = lane & 15;
    const int wm = wave >> 1, wn = wave & 1;
    const int m0 = blockIdx.y * 128, n0 = blockIdx.x * 128;

    f32x4 acc[4][4];
#pragma unroll
    for (int i = 0; i < 4; ++i)
#pragma unroll
        for (int j = 0; j < 4; ++j) acc[i][j] = (f32x4){0.f, 0.f, 0.f, 0.f};

    for (int k0 = 0; k0 < 768; k0 += 32) {
        __syncthreads();
        // stage A (128x32 fp32 -> bf16)
#pragma unroll
        for (int e = tid; e < 1024; e += 256) {
            int r = e >> 3, c4 = e & 7;
            float4 a = *(const float4*)(x + (size_t)(m0 + r) * 768 + k0 + c4 * 4);
            ushort4 p;
            p.x = (unsigned short)f2bf(a.x); p.y = (unsigned short)f2bf(a.y);
            p.z = (unsigned short)f2bf(a.z); p.w = (unsigned short)f2bf(a.w);
            *(ushort4*)&As[r][c4 * 4] = p;
        }
        // stage B transposed (32x128 fp32 -> Bs[n][k])
#pragma unroll
        for (int e = tid; e < 1024; e += 256) {
            int k = e >> 5, n4 = e & 31;
            float4 w = *(const float4*)(W + (size_t)(k0 + k) * 2304 + n0 + n4 * 4);
            Bs[n4 * 4 + 0][k] = f2bf(w.x);
            Bs[n4 * 4 + 1][k] = f2bf(w.y);
            Bs[n4 * 4 + 2][k] = f2bf(w.z);
            Bs[n4 * 4 + 3][k] = f2bf(w.w);
        }
        __syncthreads();

        bf16x8 af[4], bfr[4];
#pragma unroll
        for (int t = 0; t < 4; ++t)
            af[t] = *(const bf16x8*)&As[wm * 64 + t * 16 + l16][quad * 8];
#pragma unroll
        for (int t = 0; t < 4; ++t)
            bfr[t] = *(const bf16x8*)&Bs[wn * 64 + t * 16 + l16][quad * 8];
#pragma unroll
        for (int mt = 0; mt < 4; ++mt)
#pragma unroll
            for (int nt = 0; nt < 4; ++nt)
                acc[mt][nt] = __builtin_amdgcn_mfma_f32_16x16x32_bf16(
                    af[mt], bfr[nt], acc[mt][nt], 0, 0, 0);
    }

    // epilogue: scatter into Q/K/V [B,H,T,D]
#pragma unroll
    for (int nt = 0; nt < 4; ++nt) {
        int n = n0 + wn * 64 + nt * 16 + l16;
        float bv = bias[n];
        int which = n / 768;
        int cw = n - which * 768;
        int h = cw >> 6, d = cw & 63;
        short* dst = (which == 0) ? Qo : ((which == 1) ? Ko : Vo);
        float scale = (which == 0) ? 0.125f : 1.0f;
#pragma unroll
        for (int mt = 0; mt < 4; ++mt) {
#pragma unroll
            for (int reg = 0; reg < 4; ++reg) {
                int m = m0 + wm * 64 + mt * 16 + quad * 4 + reg;
                int b = m >> 12, t = m & 4095;
                dst[(size_t)((b * H_N + h) * T_DIM + t) * D_H + d] =
                    f2bf((acc[mt][nt][reg] + bv) * scale);
            }
        }
    }
}

// ---------------------------------------------------------------------------
// Kernel 2: causal flash attention. Q,K,V: [B*H, T, 64] bf16 (Q pre-scaled).
// Block: 64 q-rows (16/wave), kv-tiles of 64. O -> [B,T,C] bf16.
// ---------------------------------------------------------------------------
__global__ __launch_bounds__(256) void attn_kernel(
    const short* __restrict__ Q, const short* __restrict__ K,
    const short* __restrict__ V, short* __restrict__ O)
{
    __shared__ short Ks[64][72];      // [kv][d]  natural (B-operand layout)
    __shared__ short VT[64][72];      // [d][kv]  transposed (B-operand layout for PV)
    __shared__ short Ps[4][16][72];   // per-wave P relayout buffer

    const int tid  = threadIdx.x;
    const int wave = tid >> 6, lane = tid & 63;
    const int quad = lane >> 4, l16 = lane & 15;
    const int bh = blockIdx.y;
    const int b = bh / H_N, h = bh - b * H_N;
    const int q0 = ((int)gridDim.x - 1 - (int)blockIdx.x) * 64;  // heavy blocks first
    const size_t base = (size_t)bh * T_DIM * D_H;

    // Q fragments: wave owns rows q0+wave*16 .. +15 ; A-layout m=l16, k=quad*8+j
    bf16x8 qf[2];
    {
        const short* qp = Q + base + (size_t)(q0 + wave * 16 + l16) * 64 + quad * 8;
        qf[0] = *(const bf16x8*)(qp);
        qf[1] = *(const bf16x8*)(qp + 32);
    }

    f32x4 oacc[4];
#pragma unroll
    for (int i = 0; i < 4; ++i) oacc[i] = (f32x4){0.f, 0.f, 0.f, 0.f};
    float m_i[4] = {-3e38f, -3e38f, -3e38f, -3e38f};
    float l_i[4] = {0.f, 0.f, 0.f, 0.f};

    const int ntiles = q0 / 64 + 1;
    for (int it = 0; it < ntiles; ++it) {
        const int kv0 = it * 64;
        __syncthreads();
        // stage K natural
#pragma unroll
        for (int e = tid; e < 1024; e += 256) {
            int r = e >> 4, cv = e & 15;
            *(ushort4*)&Ks[r][cv * 4] =
                *(const ushort4*)(K + base + (size_t)(kv0 + r) * 64 + cv * 4);
        }
        // stage V transposed
#pragma unroll
        for (int e = tid; e < 1024; e += 256) {
            int r = e >> 4, dv = e & 15;
            ushort4 v = *(const ushort4*)(V + base + (size_t)(kv0 + r) * 64 + dv * 4);
            VT[dv * 4 + 0][r] = (short)v.x;
            VT[dv * 4 + 1][r] = (short)v.y;
            VT[dv * 4 + 2][r] = (short)v.z;
            VT[dv * 4 + 3][r] = (short)v.w;
        }
        __syncthreads();

        // S = Q K^T  (16 x 64), 4 n-tiles x 2 k-steps
        f32x4 s[4];
#pragma unroll
        for (int nt = 0; nt < 4; ++nt) s[nt] = (f32x4){0.f, 0.f, 0.f, 0.f};
#pragma unroll
        for (int nt = 0; nt < 4; ++nt) {
#pragma unroll
            for (int ks = 0; ks < 2; ++ks) {
                bf16x8 kf = *(const bf16x8*)&Ks[nt * 16 + l16][ks * 32 + quad * 8];
                s[nt] = __builtin_amdgcn_mfma_f32_16x16x32_bf16(qf[ks], kf, s[nt], 0, 0, 0);
            }
        }
        // causal mask (C-layout: row=quad*4+reg, col=nt*16+l16)
        const int qrow0 = q0 + wave * 16 + quad * 4;
#pragma unroll
        for (int nt = 0; nt < 4; ++nt) {
            int kvg = kv0 + nt * 16 + l16;
#pragma unroll
            for (int reg = 0; reg < 4; ++reg)
                if (kvg > qrow0 + reg) s[nt][reg] = -1e30f;
        }
        // online softmax (per q-row state replicated across the 16-lane group)
#pragma unroll
        for (int reg = 0; reg < 4; ++reg) {
            float rm = fmaxf(fmaxf(s[0][reg], s[1][reg]), fmaxf(s[2][reg], s[3][reg]));
            rm = fmaxf(rm, __shfl_xor(rm, 1));
            rm = fmaxf(rm, __shfl_xor(rm, 2));
            rm = fmaxf(rm, __shfl_xor(rm, 4));
            rm = fmaxf(rm, __shfl_xor(rm, 8));
            float mn = fmaxf(m_i[reg], rm);
            float alpha = __expf(m_i[reg] - mn);
            float rs = 0.f;
#pragma unroll
            for (int nt = 0; nt < 4; ++nt) {
                float p = __expf(s[nt][reg] - mn);
                s[nt][reg] = p;
                rs += p;
            }
            rs += __shfl_xor(rs, 1);
            rs += __shfl_xor(rs, 2);
            rs += __shfl_xor(rs, 4);
            rs += __shfl_xor(rs, 8);
            l_i[reg] = l_i[reg] * alpha + rs;
            m_i[reg] = mn;
#pragma unroll
            for (int nt = 0; nt < 4; ++nt) oacc[nt][reg] *= alpha;
        }
        // P: C-layout -> A-layout via per-wave LDS round-trip
#pragma unroll
        for (int nt = 0; nt < 4; ++nt)
#pragma unroll
            for (int reg = 0; reg < 4; ++reg)
                Ps[wave][quad * 4 + reg][nt * 16 + l16] = f2bf(s[nt][reg]);
        __builtin_amdgcn_s_waitcnt(0);  // intra-wave LDS RAW; lockstep wave64
        bf16x8 pf0 = *(const bf16x8*)&Ps[wave][l16][quad * 8];
        bf16x8 pf1 = *(const bf16x8*)&Ps[wave][l16][32 + quad * 8];
        // O += P V  (4 d-tiles x 2 k-steps)
#pragma unroll
        for (int nt = 0; nt < 4; ++nt) {
            bf16x8 v0 = *(const bf16x8*)&VT[nt * 16 + l16][quad * 8];
            bf16x8 v1 = *(const bf16x8*)&VT[nt * 16 + l16][32 + quad * 8];
            oacc[nt] = __builtin_amdgcn_mfma_f32_16x16x32_bf16(pf0, v0, oacc[nt], 0, 0, 0);
            oacc[nt] = __builtin_amdgcn_mfma_f32_16x16x32_bf16(pf1, v1, oacc[nt], 0, 0, 0);
        }
    }

    // normalize + store O as [B,T,C] bf16
#pragma unroll
    for (int reg = 0; reg < 4; ++reg) {
        float inv = 1.0f / l_i[reg];
        int qg = q0 + wave * 16 + quad * 4 + reg;
        size_t rowp = ((size_t)b * T_DIM + qg) * C_DIM + h * D_H;
#pragma unroll
        for (int nt = 0; nt < 4; ++nt)
            O[rowp + nt * 16 + l16] = f2bf(oacc[nt][reg] * inv);
    }
}

// ---------------------------------------------------------------------------
// Kernel 3: out = O @ Wout + bout. M=8192, K=768, N=768. grid(6,64).
// ---------------------------------------------------------------------------
__global__ __launch_bounds__(256) void out_kernel(
    const short* __restrict__ A, const float* __restrict__ W,
    const float* __restrict__ bias, float* __restrict__ out)
{
    __shared__ short As[128][40];
    __shared__ short Bs[128][40];

    const int tid  = threadIdx.x;
    const int wave = tid >> 6, lane = tid & 63;
    const int quad = lane >> 4, l16 = lane & 15;
    const int wm = wave >> 1, wn = wave & 1;
    const int m0 = blockIdx.y * 128, n0 = blockIdx.x * 128;

    f32x4 acc[4][4];
#pragma unroll
    for (int i = 0; i < 4; ++i)
#pragma unroll
        for (int j = 0; j < 4; ++j) acc[i][j] = (f32x4){0.f, 0.f, 0.f, 0.f};

    for (int k0 = 0; k0 < 768; k0 += 32) {
        __syncthreads();
#pragma unroll
        for (int e = tid; e < 512; e += 256) {
            int r = e >> 2, c8 = e & 3;
            *(bf16x8*)&As[r][c8 * 8] =
                *(const bf16x8*)(A + (size_t)(m0 + r) * 768 + k0 + c8 * 8);
        }
#pragma unroll
        for (int e = tid; e < 1024; e += 256) {
            int k = e >> 5, n4 = e & 31;
            float4 w = *(const float4*)(W + (size_t)(k0 + k) * 768 + n0 + n4 * 4);
            Bs[n4 * 4 + 0][k] = f2bf(w.x);
            Bs[n4 * 4 + 1][k] = f2bf(w.y);
            Bs[n4 * 4 + 2][k] = f2bf(w.z);
            Bs[n4 * 4 + 3][k] = f2bf(w.w);
        }
        __syncthreads();

        bf16x8 af[4], bfr[4];
#pragma unroll
        for (int t = 0; t < 4; ++t)
            af[t] = *(const bf16x8*)&As[wm * 64 + t * 16 + l16][quad * 8];
#pragma unroll
        for (int t = 0; t < 4; ++t)
            bfr[t] = *(const bf16x8*)&Bs[wn * 64 + t * 16 + l16][quad * 8];
#pragma unroll
        for (int mt = 0; mt < 4; ++mt)
#pragma unroll
            for (int nt = 0; nt < 4; ++nt)
                acc[mt][nt] = __builtin_amdgcn_mfma_f32_16x16x32_bf16(
                    af[mt], bfr[nt], acc[mt][nt], 0, 0, 0);
    }

#pragma unroll
    for (int nt = 0; nt < 4; ++nt) {
        int n = n0 + wn * 64 + nt * 16 + l16;
        float bv = bias[n];
#pragma unroll
        for (int mt = 0; mt < 4; ++mt) {
#pragma unroll
            for (int reg = 0; reg < 4; ++reg) {
                int m = m0 + wm * 64 + mt * 16 + quad * 4 + reg;
                out[(size_t)m * 768 + n] = acc[mt][nt][reg] + bv;
            }
        }
    }
}

// ---------------------------------------------------------------------------
extern "C" void kernel_launch(void* const* d_in, const int* in_sizes, int n_in,
                              void* d_out, int out_size, void* d_ws, size_t ws_size,
                              hipStream_t stream) {
    const float* x    = (const float*)d_in[0];
    const float* Wqkv = (const float*)d_in[1];
    const float* bqkv = (const float*)d_in[2];
    const float* Wout = (const float*)d_in[3];
    const float* bout = (const float*)d_in[4];
    float* out = (float*)d_out;

    const size_t per = (size_t)B_N * H_N * T_DIM * D_H;  // 6291456 bf16 elems
    short* Q = (short*)d_ws;
    short* K = Q + per;
    short* V = K + per;
    short* O = V + per;   // [B,T,C] bf16 attn output

    qkv_kernel<<<dim3(18, 64), 256, 0, stream>>>(x, Wqkv, bqkv, Q, K, V);
    attn_kernel<<<dim3(64, B_N * H_N), 256, 0, stream>>>(Q, K, V, O);
    out_kernel<<<dim3(6, 64), 256, 0, stream>>>(O, Wout, bout, out);
}